// Round 1
// baseline (317.685 us; speedup 1.0000x reference)
//
#include <hip/hip_runtime.h>

#define KSIZE 7
#define NEG_INF (-1e30f)
#define IMG_H 512
#define IMG_W 512
#define C_PT 4                 // output cols per thread (one float4)
#define R_PT 8                 // output rows per thread
#define TILE_W 128             // 32 threads * 4 cols
#define TILE_H 64              // 8 thread-rows * 8 rows

// fmaxf(a, fmaxf(b, c)) -> v_max3_f32
#define M3(a, b, c) fmaxf((a), fmaxf((b), (c)))

__global__ __launch_bounds__(256, 4)
void GrayscaleDilation2D_kernel(const float* __restrict__ img,
                                const float* __restrict__ filt,
                                float* __restrict__ out) {
    const int plane = blockIdx.z;
    const int x0 = blockIdx.x * TILE_W;
    const int y0 = blockIdx.y * TILE_H;
    const float* __restrict__ src = img + (size_t)plane * IMG_H * IMG_W;
    float* __restrict__ dst = out + (size_t)plane * IMG_H * IMG_W;

    const int tx = threadIdx.x;          // 0..31
    const int ty = threadIdx.y;          // 0..7
    const int col0 = x0 + tx * C_PT;     // output col base
    const int row0 = y0 + ty * R_PT;     // output row base
    const int gxw = col0 - 4;            // 12-float window start, float4-aligned

    // Filter: uniform address + constant indices -> s_load into SGPRs.
    float sf[KSIZE * KSIZE];
#pragma unroll
    for (int k = 0; k < KSIZE * KSIZE; ++k) sf[k] = filt[k];

    // Column-validity flags (per-thread constants; only edge threads differ).
    // Window float4s cover cols [gxw, gxw+4), [col0, col0+4), [col0+4, col0+8).
    const bool cok0 = (gxw >= 0);               // false only at image left edge
    const bool cok2 = (col0 + 4 < IMG_W);       // false only at image right edge

    float acc[R_PT][C_PT];
#pragma unroll
    for (int o = 0; o < R_PT; ++o)
#pragma unroll
        for (int l = 0; l < C_PT; ++l) acc[o][l] = NEG_INF;

    // Stream input rows gy = row0-3 .. row0+R_PT+2 straight from global (L1/L2
    // serves the halo overlap between threads; no LDS, no barrier).
#pragma unroll
    for (int r = 0; r < R_PT + 6; ++r) {
        const int gy = row0 - 3 + r;
        const bool rok = ((unsigned)gy < IMG_H);
        const float* rp = src + (size_t)gy * IMG_W + gxw;
        float4 A = make_float4(NEG_INF, NEG_INF, NEG_INF, NEG_INF);
        float4 B = A;
        float4 C = A;
        if (rok) {
            if (cok0) A = *(const float4*)(rp);
            B = *(const float4*)(rp + 4);            // always in-bounds
            if (cok2) C = *(const float4*)(rp + 8);
        }
        // Window col gxw+k holds input col col0+k-4; tap (l,j) needs v[1+l+j].
        const float v[12] = {A.x, A.y, A.z, A.w, B.x, B.y, B.z, B.w,
                             C.x, C.y, C.z, C.w};
        const int omin = (r - 6 < 0) ? 0 : r - 6;
        const int omax = (r < R_PT - 1) ? r : R_PT - 1;
#pragma unroll
        for (int o = 0; o < R_PT; ++o) {
            if (o < omin || o > omax) continue;   // static after unroll
            const int i = r - o;                  // filter row
            const float* fr = &sf[i * KSIZE];
#pragma unroll
            for (int l = 0; l < C_PT; ++l) {
                const float t0 = v[1 + l + 0] + fr[0];
                const float t1 = v[1 + l + 1] + fr[1];
                const float t2 = v[1 + l + 2] + fr[2];
                const float t3 = v[1 + l + 3] + fr[3];
                const float t4 = v[1 + l + 4] + fr[4];
                const float t5 = v[1 + l + 5] + fr[5];
                const float t6 = v[1 + l + 6] + fr[6];
                // 4 instrs: 3x v_max3_f32 + 1x v_max_f32
                const float u = M3(t0, t1, t2);
                const float w = M3(t3, t4, t5);
                const float z = M3(acc[o][l], t6, u);
                acc[o][l] = fmaxf(z, w);
            }
        }
    }

#pragma unroll
    for (int o = 0; o < R_PT; ++o) {
        float4 res = make_float4(acc[o][0], acc[o][1], acc[o][2], acc[o][3]);
        *(float4*)&dst[(size_t)(row0 + o) * IMG_W + col0] = res;
    }
}

extern "C" void kernel_launch(void* const* d_in, const int* in_sizes, int n_in,
                              void* d_out, int out_size, void* d_ws, size_t ws_size,
                              hipStream_t stream) {
    const float* img  = (const float*)d_in[0];
    const float* filt = (const float*)d_in[1];
    float* out = (float*)d_out;

    const int planes = in_sizes[0] / (IMG_H * IMG_W);  // B*C = 128
    dim3 grid(IMG_W / TILE_W, IMG_H / TILE_H, planes);
    dim3 block(32, 8);
    hipLaunchKernelGGL(GrayscaleDilation2D_kernel, grid, block, 0, stream,
                       img, filt, out);
}

// Round 2
// 260.183 us; speedup vs baseline: 1.2210x; 1.2210x over previous
//
#include <hip/hip_runtime.h>

#define KSIZE 7
#define NEG_INF (-1e30f)
#define TILE_W 128
#define TILE_H 32
#define HALO_L 4                     // left halo padded to 4 for float4 alignment
#define REG_W 136                    // TILE_W + 4 left + 4 right
#define REG_H 38                     // TILE_H + 6
#define LDS_STRIDE 136               // == REG_W, multiple of 4 floats
#define IMG_H 512
#define IMG_W 512
#define N_VEC4 (REG_W / 4)           // 34 float4 per row
#define TOT_VEC4 (REG_H * N_VEC4)    // 1292 float4 slots

// <2 x float> — fadd lowers to v_pk_add_f32 on gfx90a+ (packed fp32 ops)
typedef float pk2 __attribute__((ext_vector_type(2)));

// fmaxf(a, fmaxf(b, c)) -> v_max3_f32
#define M3(a, b, c) fmaxf((a), fmaxf((b), (c)))

static __device__ __forceinline__ pk2 mk2(float a, float b) {
    pk2 r; r.x = a; r.y = b; return r;
}

// One filter-row contribution to one output: taps t_j = v[1+l+j] + f[j].
// Pairs (j, j+1) for j = 0,2,4 are packed adds; j=6 scalar. Max tree identical
// in value to the scalar version (max is exactly associative/commutative).
static __device__ __forceinline__ float dil_body(float acc, pk2 a, pk2 b, pk2 c,
                                                 float t6v, pk2 f01, pk2 f23,
                                                 pk2 f45, float f6) {
    const pk2 t01 = a + f01;          // v_pk_add_f32
    const pk2 t23 = b + f23;
    const pk2 t45 = c + f45;
    const float t6 = t6v + f6;
    const float u = M3(t01.x, t01.y, t23.x);
    const float w = M3(t23.y, t45.x, t45.y);
    const float z = M3(acc, t6, u);
    return fmaxf(z, w);
}

__global__ __launch_bounds__(256)
void GrayscaleDilation2D_kernel(const float* __restrict__ img,
                                const float* __restrict__ filt,
                                float* __restrict__ out) {
    __shared__ float tile[REG_H * LDS_STRIDE];

    const int plane = blockIdx.z;
    const int x0 = blockIdx.x * TILE_W;
    const int y0 = blockIdx.y * TILE_H;
    const float* __restrict__ src = img + (size_t)plane * IMG_H * IMG_W;
    float* __restrict__ dst = out + (size_t)plane * IMG_H * IMG_W;

    const int tx = threadIdx.x;  // 0..31
    const int ty = threadIdx.y;  // 0..7
    const int t = ty * 32 + tx;

    // Filter prepacked as float2 pairs (f[i][2p], f[i][2p+1]) + scalar f[i][6].
    // Uniform addresses + constant indices -> scalar loads, SGPR pairs.
    pk2 fp[KSIZE][3];
    float f6[KSIZE];
#pragma unroll
    for (int i = 0; i < KSIZE; ++i) {
        const float* fr = filt + i * KSIZE;
        fp[i][0] = mk2(fr[0], fr[1]);
        fp[i][1] = mk2(fr[2], fr[3]);
        fp[i][2] = mk2(fr[4], fr[5]);
        f6[i] = fr[6];
    }

    // Stage (REG_H x REG_W) region into LDS as aligned float4 (unchanged).
#pragma unroll
    for (int it = 0; it < 6; ++it) {
        const int idx = t + it * 256;
        if (idx < TOT_VEC4) {
            const int r  = idx / N_VEC4;
            const int c4 = idx - r * N_VEC4;
            const int gy = y0 - 3 + r;
            const int gx = x0 - HALO_L + c4 * 4;
            float4 v4 = make_float4(NEG_INF, NEG_INF, NEG_INF, NEG_INF);
            if ((unsigned)gy < IMG_H && (unsigned)gx < IMG_W)
                v4 = *(const float4*)&src[gy * IMG_W + gx];
            *(float4*)&tile[r * LDS_STRIDE + c4 * 4] = v4;
        }
    }
    __syncthreads();

    // Each thread: 4x4 output tile. rows y0+ty*4+o, cols x0+tx*4+l.
    float acc[4][4];
#pragma unroll
    for (int o = 0; o < 4; ++o)
#pragma unroll
        for (int l = 0; l < 4; ++l) acc[o][l] = NEG_INF;

    const int row0 = ty * 4;
    const int col0 = tx * 4;

#pragma unroll
    for (int r = 0; r < 10; ++r) {
        const float* rp = &tile[(row0 + r) * LDS_STRIDE + col0];
        // Natural even pairs e[m] = (v[2m], v[2m+1]): 5x ds_read_b64
        // (lane stride 8B -> 2-way bank aliasing, free; vs b128's 4-way).
        const pk2 e0 = *(const pk2*)(rp);
        const pk2 e1 = *(const pk2*)(rp + 2);
        const pk2 e2 = *(const pk2*)(rp + 4);
        const pk2 e3 = *(const pk2*)(rp + 6);
        const pk2 e4 = *(const pk2*)(rp + 8);
        const float v10 = rp[10];               // only scalar tap of last slot
        // Odd pairs q[m] = (v[2m+1], v[2m+2]), shared by all o-bodies this row.
        const pk2 q0 = __builtin_shufflevector(e0, e1, 1, 2);
        const pk2 q1 = __builtin_shufflevector(e1, e2, 1, 2);
        const pk2 q2 = __builtin_shufflevector(e2, e3, 1, 2);
        const pk2 q3 = __builtin_shufflevector(e3, e4, 1, 2);

        const int omin = (r - 6 < 0) ? 0 : r - 6;
        const int omax = (r < 3) ? r : 3;
#pragma unroll
        for (int o = 0; o < 4; ++o) {
            if (o < omin || o > omax) continue;  // static after unroll
            const int i = r - o;                 // filter row
            // l=0: v1..v7  -> q0,q1,q2, t6=v7=e3.y
            acc[o][0] = dil_body(acc[o][0], q0, q1, q2, e3.y,
                                 fp[i][0], fp[i][1], fp[i][2], f6[i]);
            // l=1: v2..v8  -> e1,e2,e3, t6=v8=e4.x
            acc[o][1] = dil_body(acc[o][1], e1, e2, e3, e4.x,
                                 fp[i][0], fp[i][1], fp[i][2], f6[i]);
            // l=2: v3..v9  -> q1,q2,q3, t6=v9=e4.y
            acc[o][2] = dil_body(acc[o][2], q1, q2, q3, e4.y,
                                 fp[i][0], fp[i][1], fp[i][2], f6[i]);
            // l=3: v4..v10 -> e2,e3,e4, t6=v10
            acc[o][3] = dil_body(acc[o][3], e2, e3, e4, v10,
                                 fp[i][0], fp[i][1], fp[i][2], f6[i]);
        }
    }

#pragma unroll
    for (int o = 0; o < 4; ++o) {
        float4 res = make_float4(acc[o][0], acc[o][1], acc[o][2], acc[o][3]);
        *(float4*)&dst[(size_t)(y0 + row0 + o) * IMG_W + (x0 + col0)] = res;
    }
}

extern "C" void kernel_launch(void* const* d_in, const int* in_sizes, int n_in,
                              void* d_out, int out_size, void* d_ws, size_t ws_size,
                              hipStream_t stream) {
    const float* img  = (const float*)d_in[0];
    const float* filt = (const float*)d_in[1];
    float* out = (float*)d_out;

    const int planes = in_sizes[0] / (IMG_H * IMG_W);  // B*C = 128
    dim3 grid(IMG_W / TILE_W, IMG_H / TILE_H, planes);
    dim3 block(32, 8);
    hipLaunchKernelGGL(GrayscaleDilation2D_kernel, grid, block, 0, stream,
                       img, filt, out);
}